// Round 7
// baseline (1899.081 us; speedup 1.0000x reference)
//
#include <hip/hip_runtime.h>
#include <hip/hip_bf16.h>

// UnrolledRNN on MI355X (gfx950) — two-phase; flag-synced (barrier-free) recurrence.
// Phase 1 (parallel, all CUs): xh[b,t,:] = x[b,t,:] @ Wxh + bxh -> bf16 in d_ws.
// Phase 2 (serial, 16 blocks x 4 waves): h = tanh(xh_t + h @ Whh_sigma).
//   R2/R3/R6 all converged at ~1160 cyc/step regardless of per-step work =>
//   the per-step s_barrier rendezvous (~500-600 cyc at 1 wave/SIMD) is the
//   floor. This version replaces it with MONOTONIC PER-WAVE FLAGS in LDS:
//     publish frag -> lgkmcnt(0) -> lane0 writes flag[wv] = t+2
//     consumers spin-poll the 3 foreign flags (volatile broadcast reads).
//   Safety: flag>=t+1 => that wave finished step t-1 => its reads of h_{t-1}
//   (same parity zone as the h_{t+1} being written) are done -> WAR-safe with
//   2-zone parity. DS ops are in-order per wave; flag-after-data enforced by
//   lgkmcnt(0). Max skew = 1 step. One s_barrier at init only (flag validity).
//   sigma exchange (validated R3): wave wv's packed tanh output IS its own
//   next-step B-frag; 1 lane-linear ds_write publishes, 3 lane-linear
//   ds_reads fetch foreign frags (conflict-free, measured 0).

#define SEQ   2048
#define HID   128
#define BATCH 256
#define BD    16

typedef __attribute__((ext_vector_type(8))) short    short8;
typedef __attribute__((ext_vector_type(4))) float    f32x4;
typedef __attribute__((ext_vector_type(4))) float    f4;
typedef __attribute__((ext_vector_type(2))) unsigned u32x2;
typedef __attribute__((ext_vector_type(4))) unsigned u32x4;

union F8 { unsigned u[4]; short8 s; };

__device__ __forceinline__ unsigned pkbf(float a, float b) {
    union { __hip_bfloat16 h[2]; unsigned u; } t;
    t.h[0] = __float2bfloat16(a);
    t.h[1] = __float2bfloat16(b);
    return t.u;
}

__device__ __forceinline__ float blo(unsigned u) {
    union { unsigned v; float f; } t; t.v = u << 16; return t.f;
}
__device__ __forceinline__ float bhi(unsigned u) {
    union { unsigned v; float f; } t; t.v = u & 0xffff0000u; return t.f;
}

__device__ __forceinline__ float tanh_fast(float x) {
    float e = __builtin_amdgcn_exp2f(x * 2.8853900817779268f);
    return 1.0f - 2.0f * __builtin_amdgcn_rcpf(e + 1.0f);
}

__device__ __forceinline__ void block_sync() {
    asm volatile("s_waitcnt lgkmcnt(0)" ::: "memory");
    __builtin_amdgcn_s_barrier();
    asm volatile("" ::: "memory");
}

#define MFMA16(A,B,C) __builtin_amdgcn_mfma_f32_16x16x32_bf16((A),(B),(C),0,0,0)

// =====================================================================
// Phase 1: xh = x @ Wxh + bxh, bf16 [BATCH*SEQ][HID] in ws (plain j order).
// =====================================================================
__launch_bounds__(256, 1)
__global__ void xh_gemm_kernel(const float* __restrict__ x,
                               const float* __restrict__ Wxh,
                               const float* __restrict__ bxh,
                               __hip_bfloat16* __restrict__ xh)
{
    const int tid  = threadIdx.x;
    const int wv   = tid >> 6;
    const int lane = tid & 63;
    const int lg   = lane >> 4;
    const int lm   = lane & 15;

    const int gw = blockIdx.x * 4 + wv;
    const int NW = gridDim.x * 4;
    const int NT = (BATCH * SEQ) / 16;

    short8 wa[8][4];
    {
        #pragma unroll
        for (int T = 0; T < 8; ++T) {
            #pragma unroll
            for (int c = 0; c < 4; ++c) {
                F8 f;
                #pragma unroll
                for (int e2 = 0; e2 < 4; ++e2) {
                    int k = 32*c + 8*lg + 2*e2;
                    f.u[e2] = pkbf(Wxh[(size_t)k*HID + 16*T + lm],
                                   Wxh[(size_t)(k+1)*HID + 16*T + lm]);
                }
                wa[T][c] = f.s;
            }
        }
    }
    float bb[8][4];
    #pragma unroll
    for (int T = 0; T < 8; ++T)
        #pragma unroll
        for (int r = 0; r < 4; ++r)
            bb[T][r] = bxh[16*T + 4*lg + r];

    for (int tile = gw; tile < NT; tile += NW) {
        const float* xp = x + (size_t)tile*16*HID + (size_t)lm*HID + 8*lg;
        f4 s[8];
        #pragma unroll
        for (int c = 0; c < 4; ++c) {
            s[2*c]   = *(const f4*)(xp + 32*c);
            s[2*c+1] = *(const f4*)(xp + 32*c + 4);
        }
        F8 xf[4];
        #pragma unroll
        for (int c = 0; c < 4; ++c) {
            xf[c].u[0] = pkbf(s[2*c][0],   s[2*c][1]);
            xf[c].u[1] = pkbf(s[2*c][2],   s[2*c][3]);
            xf[c].u[2] = pkbf(s[2*c+1][0], s[2*c+1][1]);
            xf[c].u[3] = pkbf(s[2*c+1][2], s[2*c+1][3]);
        }
        __hip_bfloat16* op = xh + (size_t)(tile*16 + lm) * HID;
        #pragma unroll
        for (int T = 0; T < 8; ++T) {
            f32x4 acc = {bb[T][0], bb[T][1], bb[T][2], bb[T][3]};
            #pragma unroll
            for (int c = 0; c < 4; ++c)
                acc = MFMA16(wa[T][c], xf[c].s, acc);
            u32x2 w;
            w[0] = pkbf(acc[0], acc[1]);
            w[1] = pkbf(acc[2], acc[3]);
            *reinterpret_cast<u32x2*>(op + 16*T + 4*lg) = w;
        }
    }
}

// =====================================================================
// Phase 2: flag-synced sigma recurrence.
// LDS: zone[P in 0..1][c in 0..3][lane][16B] at P*4096 + c*1024 + lane*16;
// flags (4 ints) at byte 8192.
// =====================================================================

#define RECFF_STEP(S, P, POFF, TRT)                                           \
    {                                                                          \
        f32x4 a0, a1;                                                          \
        a0[0] = blo(S[0]); a0[1] = bhi(S[0]);                                  \
        a0[2] = blo(S[1]); a0[3] = bhi(S[1]);                                  \
        a1[0] = blo(S[2]); a1[1] = bhi(S[2]);                                  \
        a1[2] = blo(S[3]); a1[3] = bhi(S[3]);                                  \
        if ((TRT) + 4 < SEQ) S = *(const u32x4*)(xq + (POFF)*256);             \
        /* self-frag MFMAs: independent of other waves, issue pre-poll */      \
        a0 = MFMA16(whhf[0][3], self, a0);                                     \
        a1 = MFMA16(whhf[1][3], self, a1);                                     \
        {                                                                      \
            const int tgt = (TRT) + 1;                                         \
            while (pfA[0] < tgt || pfB[0] < tgt || pfC[0] < tgt) { }           \
        }                                                                      \
        asm volatile("" ::: "memory");                                         \
        const char* rb = lds + (P)*4096;                                       \
        short8 fA = *(const short8*)(rb + rdA);                                \
        short8 fB = *(const short8*)(rb + rdB);                                \
        short8 fC = *(const short8*)(rb + rdC);                                \
        f32x4 t0 = {0.f,0.f,0.f,0.f}, t1 = {0.f,0.f,0.f,0.f};                  \
        t0 = MFMA16(whhf[0][0], fA, t0);                                       \
        t1 = MFMA16(whhf[1][0], fA, t1);                                       \
        a0 = MFMA16(whhf[0][1], fB, a0);                                       \
        a1 = MFMA16(whhf[1][1], fB, a1);                                       \
        t0 = MFMA16(whhf[0][2], fC, t0);                                       \
        t1 = MFMA16(whhf[1][2], fC, t1);                                       \
        a0 += t0; a1 += t1;                                                    \
        F8 nf;                                                                 \
        nf.u[0] = pkbf(tanh_fast(a0[0]), tanh_fast(a0[1]));                    \
        nf.u[1] = pkbf(tanh_fast(a0[2]), tanh_fast(a0[3]));                    \
        nf.u[2] = pkbf(tanh_fast(a1[0]), tanh_fast(a1[1]));                    \
        nf.u[3] = pkbf(tanh_fast(a1[2]), tanh_fast(a1[3]));                    \
        self = nf.s;                                                           \
        *reinterpret_cast<short8*>(lds + ((P)^1)*4096 + wrO) = self;           \
        asm volatile("s_waitcnt lgkmcnt(0)" ::: "memory");                     \
        if (lane == 0) myf[0] = (TRT) + 2;                                     \
    }

__launch_bounds__(256, 1)
__global__ void rnn_recff_kernel(const __hip_bfloat16* __restrict__ xh,
                                 const float* __restrict__ h0,
                                 const float* __restrict__ Whh,
                                 const float* __restrict__ Wout,
                                 const float* __restrict__ bout,
                                 float* __restrict__ out)
{
    __shared__ __align__(16) char lds[8192 + 16];  // 2 zones + 4 flags

    const int tid  = threadIdx.x;
    const int wv   = tid >> 6;
    const int lane = tid & 63;
    const int lg   = lane >> 4;
    const int lm   = lane & 15;
    const int b0   = blockIdx.x * BD;

    const int cA = (wv + 1) & 3, cB = (wv + 2) & 3, cC = (wv + 3) & 3;
    // whhf[u][idx]: idx 0,1,2 = frags cA,cB,cC; idx 3 = self (c=wv).
    // A-frag for acc u: lane (lg,lm) elem e = Whh[32c+8lg+e][sigma(u,lm)],
    // sigma(u,row) = 32wv + 8*(row>>2) + 4u + (row&3).
    short8 whhf[2][4];
    {
        const int scol = 32*wv + 8*(lm >> 2) + (lm & 3);
        const int cs[4] = {cA, cB, cC, wv};
        #pragma unroll
        for (int u = 0; u < 2; ++u) {
            #pragma unroll
            for (int ci = 0; ci < 4; ++ci) {
                const int c = cs[ci];
                F8 f;
                #pragma unroll
                for (int e2 = 0; e2 < 4; ++e2) {
                    int k = 32*c + 8*lg + 2*e2;
                    f.u[e2] = pkbf(Whh[(size_t)k*HID + scol + 4*u],
                                   Whh[(size_t)(k+1)*HID + scol + 4*u]);
                }
                whhf[u][ci] = f.s;
            }
        }
    }

    // lane-linear LDS offsets (zone-relative; conflict-free)
    const int rdA = cA*1024 + lane*16;
    const int rdB = cB*1024 + lane*16;
    const int rdC = cC*1024 + lane*16;
    const int wrO = wv*1024 + lane*16;

    // flag pointers
    volatile int* flg = (volatile int*)(lds + 8192);
    volatile int* myf = flg + wv;
    volatile const int* pfA = flg + cA;
    volatile const int* pfB = flg + cB;
    volatile const int* pfC = flg + cC;

    // init: self-frag from h0; publish to zone0; flag = 1; ONE barrier so all
    // flag cells are valid before any poll (LDS is uninitialized at start).
    short8 self;
    {
        const float* hp = h0 + (size_t)(b0 + lm) * HID + 32*wv + 8*lg;
        f4 v0 = *(const f4*)(hp);
        f4 v1 = *(const f4*)(hp + 4);
        F8 f;
        f.u[0] = pkbf(v0[0], v0[1]); f.u[1] = pkbf(v0[2], v0[3]);
        f.u[2] = pkbf(v1[0], v1[1]); f.u[3] = pkbf(v1[2], v1[3]);
        self = f.s;
        *reinterpret_cast<short8*>(lds + wrO) = self;
        asm volatile("s_waitcnt lgkmcnt(0)" ::: "memory");
        if (lane == 0) myf[0] = 1;
    }
    block_sync();

    // xh stream: one dwordx4 per step = xh[b0+lm][t][32wv+8lg .. +7]
    const char* xq = (const char*)xh + (size_t)(b0 + lm) * SEQ * 256
                   + 64*wv + 16*lg;

    u32x4 sA = *(const u32x4*)(xq + 0*256);
    u32x4 sB = *(const u32x4*)(xq + 1*256);
    u32x4 sC = *(const u32x4*)(xq + 2*256);
    u32x4 sD = *(const u32x4*)(xq + 3*256);

    for (int t = 0; t < SEQ; t += 4) {
        RECFF_STEP(sA, 0, 4, t);
        RECFF_STEP(sB, 1, 5, t + 1);
        RECFF_STEP(sC, 0, 6, t + 2);
        RECFF_STEP(sD, 1, 7, t + 3);
        xq += 4 * 256;
    }

    // epilogue: out = h_last @ Wout + bout; h_SEQ frags in zone0.
    {
        const int tgt = SEQ + 1;
        while (pfA[0] < tgt || pfB[0] < tgt || pfC[0] < tgt) { }
    }
    asm volatile("" ::: "memory");
    {
        short8 wof[2][4];
        const int col = 32*wv + lm;
        #pragma unroll
        for (int T = 0; T < 2; ++T) {
            #pragma unroll
            for (int c = 0; c < 4; ++c) {
                F8 f;
                #pragma unroll
                for (int e2 = 0; e2 < 4; ++e2) {
                    int k = 32*c + 8*lg + 2*e2;
                    f.u[e2] = pkbf(Wout[(size_t)k*HID + col + 16*T],
                                   Wout[(size_t)(k+1)*HID + col + 16*T]);
                }
                wof[T][c] = f.s;
            }
        }
        f32x4 o0 = {bout[32*wv + 4*lg + 0], bout[32*wv + 4*lg + 1],
                    bout[32*wv + 4*lg + 2], bout[32*wv + 4*lg + 3]};
        f32x4 o1 = {bout[32*wv + 16 + 4*lg + 0], bout[32*wv + 16 + 4*lg + 1],
                    bout[32*wv + 16 + 4*lg + 2], bout[32*wv + 16 + 4*lg + 3]};
        #pragma unroll
        for (int c = 0; c < 4; ++c) {
            short8 hf = *reinterpret_cast<const short8*>(lds + c*1024 + lane*16);
            o0 = MFMA16(wof[0][c], hf, o0);
            o1 = MFMA16(wof[1][c], hf, o1);
        }
        float* op = out + (size_t)(b0 + lm) * HID + 32*wv + 4*lg;
        *reinterpret_cast<f4*>(op)      = o0;
        *reinterpret_cast<f4*>(op + 16) = o1;
    }
}

// =====================================================================
// Fallback: verified round-1 monolithic kernel (used if ws too small).
// =====================================================================
#define RNN_STEP(SLOT, P, POFF, TRT)                                          \
    {                                                                          \
        F8 xf[4];                                                              \
        _Pragma("unroll")                                                      \
        for (int c = 0; c < 4; ++c) {                                          \
            xf[c].u[0] = pkbf(SLOT[2*c][0],   SLOT[2*c][1]);                   \
            xf[c].u[1] = pkbf(SLOT[2*c][2],   SLOT[2*c][3]);                   \
            xf[c].u[2] = pkbf(SLOT[2*c+1][0], SLOT[2*c+1][1]);                 \
            xf[c].u[3] = pkbf(SLOT[2*c+1][2], SLOT[2*c+1][3]);                 \
        }                                                                      \
        if ((TRT) + 2 < SEQ) {                                                 \
            _Pragma("unroll")                                                  \
            for (int c = 0; c < 4; ++c) {                                      \
                SLOT[2*c]   = *(const f4*)(xq + (POFF)*HID + 32*c);            \
                SLOT[2*c+1] = *(const f4*)(xq + (POFF)*HID + 32*c + 4);        \
            }                                                                  \
        }                                                                      \
        f32x4 a0 = {bx[0][0], bx[0][1], bx[0][2], bx[0][3]};                   \
        f32x4 a1 = {bx[1][0], bx[1][1], bx[1][2], bx[1][3]};                   \
        _Pragma("unroll")                                                      \
        for (int c = 0; c < 4; ++c) {                                          \
            a0 = MFMA16(wxh[0][c], xf[c].s, a0);                               \
            a1 = MFMA16(wxh[1][c], xf[c].s, a1);                               \
        }                                                                      \
        block_sync();                                                          \
        _Pragma("unroll")                                                      \
        for (int c = 0; c < 4; ++c) {                                          \
            short8 hf = *reinterpret_cast<const short8*>(lds + (P)*4096 + rd[c]); \
            a0 = MFMA16(whh[0][c], hf, a0);                                    \
            a1 = MFMA16(whh[1][c], hf, a1);                                    \
        }                                                                      \
        u32x2 w0, w1;                                                          \
        w0[0] = pkbf(tanh_fast(a0[0]), tanh_fast(a0[1]));                      \
        w0[1] = pkbf(tanh_fast(a0[2]), tanh_fast(a0[3]));                      \
        w1[0] = pkbf(tanh_fast(a1[0]), tanh_fast(a1[1]));                      \
        w1[1] = pkbf(tanh_fast(a1[2]), tanh_fast(a1[3]));                      \
        *reinterpret_cast<u32x2*>(lds + ((P)^1)*4096 + hw[0]) = w0;            \
        *reinterpret_cast<u32x2*>(lds + ((P)^1)*4096 + hw[1]) = w1;            \
    }

__launch_bounds__(256, 1)
__global__ void rnn_fused_kernel(const float* __restrict__ x,
                                 const float* __restrict__ h0,
                                 const float* __restrict__ Wxh,
                                 const float* __restrict__ bxh,
                                 const float* __restrict__ Whh,
                                 const float* __restrict__ Wout,
                                 const float* __restrict__ bout,
                                 float* __restrict__ out)
{
    __shared__ __align__(16) char lds[2 * 4096];

    const int tid  = threadIdx.x;
    const int wv   = tid >> 6;
    const int lane = tid & 63;
    const int lg   = lane >> 4;
    const int lm   = lane & 15;
    const int b0   = blockIdx.x * BD;

    short8 wxh[2][4], whh[2][4];
    {
        const int col = 32*wv + lm;
        #pragma unroll
        for (int T = 0; T < 2; ++T) {
            #pragma unroll
            for (int c = 0; c < 4; ++c) {
                F8 fx, fh;
                #pragma unroll
                for (int e2 = 0; e2 < 4; ++e2) {
                    int k = 32*c + 8*lg + 2*e2;
                    fx.u[e2] = pkbf(Wxh[(size_t)k*HID + col + 16*T],
                                    Wxh[(size_t)(k+1)*HID + col + 16*T]);
                    fh.u[e2] = pkbf(Whh[(size_t)k*HID + col + 16*T],
                                    Whh[(size_t)(k+1)*HID + col + 16*T]);
                }
                wxh[T][c] = fx.s; whh[T][c] = fh.s;
            }
        }
    }
    float bx[2][4];
    #pragma unroll
    for (int T = 0; T < 2; ++T)
        #pragma unroll
        for (int r = 0; r < 4; ++r)
            bx[T][r] = bxh[32*wv + 16*T + 4*lg + r];

    int rd[4];
    #pragma unroll
    for (int c = 0; c < 4; ++c)
        rd[c] = (lm*256 + 64*c + 16*lg) ^ ((lm & 7) << 4);
    int hw[2];
    #pragma unroll
    for (int T = 0; T < 2; ++T)
        hw[T] = (lm*256 + 2*(32*wv + 16*T + 4*lg)) ^ ((lm & 7) << 4);

    {
        int b  = tid >> 4;
        int j0 = (tid & 15) * 8;
        const float* hp = h0 + (size_t)(b0 + b) * HID + j0;
        f4 v0 = *(const f4*)(hp);
        f4 v1 = *(const f4*)(hp + 4);
        F8 f;
        f.u[0] = pkbf(v0[0], v0[1]); f.u[1] = pkbf(v0[2], v0[3]);
        f.u[2] = pkbf(v1[0], v1[1]); f.u[3] = pkbf(v1[2], v1[3]);
        int off = (b*256 + 2*j0) ^ ((b & 7) << 4);
        *reinterpret_cast<short8*>(lds + off) = f.s;
    }

    const float* xq = x + (size_t)(b0 + lm) * SEQ * HID + 8*lg;
    f4 sA[8], sB[8];
    #pragma unroll
    for (int c = 0; c < 4; ++c) {
        sA[2*c]   = *(const f4*)(xq + 32*c);
        sA[2*c+1] = *(const f4*)(xq + 32*c + 4);
        sB[2*c]   = *(const f4*)(xq + HID + 32*c);
        sB[2*c+1] = *(const f4*)(xq + HID + 32*c + 4);
    }

    for (int t = 0; t < SEQ; t += 2) {
        RNN_STEP(sA, 0, 2, t);
        RNN_STEP(sB, 1, 3, t + 1);
        xq += 2 * HID;
    }

    block_sync();
    {
        short8 wo[2][4];
        const int col = 32*wv + lm;
        #pragma unroll
        for (int T = 0; T < 2; ++T) {
            #pragma unroll
            for (int c = 0; c < 4; ++c) {
                F8 f;
                #pragma unroll
                for (int e2 = 0; e2 < 4; ++e2) {
                    int k = 32*c + 8*lg + 2*e2;
                    f.u[e2] = pkbf(Wout[(size_t)k*HID + col + 16*T],
                                   Wout[(size_t)(k+1)*HID + col + 16*T]);
                }
                wo[T][c] = f.s;
            }
        }
        f32x4 o0 = {bout[32*wv + 4*lg + 0], bout[32*wv + 4*lg + 1],
                    bout[32*wv + 4*lg + 2], bout[32*wv + 4*lg + 3]};
        f32x4 o1 = {bout[32*wv + 16 + 4*lg + 0], bout[32*wv + 16 + 4*lg + 1],
                    bout[32*wv + 16 + 4*lg + 2], bout[32*wv + 16 + 4*lg + 3]};
        #pragma unroll
        for (int c = 0; c < 4; ++c) {
            short8 hf = *reinterpret_cast<const short8*>(lds + rd[c]);
            o0 = MFMA16(wo[0][c], hf, o0);
            o1 = MFMA16(wo[1][c], hf, o1);
        }
        float* op = out + (size_t)(b0 + lm) * HID + 32*wv + 4*lg;
        *reinterpret_cast<f4*>(op)      = o0;
        *reinterpret_cast<f4*>(op + 16) = o1;
    }
}

extern "C" void kernel_launch(void* const* d_in, const int* in_sizes, int n_in,
                              void* d_out, int out_size, void* d_ws, size_t ws_size,
                              hipStream_t stream) {
    const float* x    = (const float*)d_in[0];
    const float* h0   = (const float*)d_in[1];
    const float* Wxh  = (const float*)d_in[2];
    const float* bxh  = (const float*)d_in[3];
    const float* Whh  = (const float*)d_in[4];
    const float* Wout = (const float*)d_in[5];
    const float* bout = (const float*)d_in[6];
    (void)in_sizes; (void)n_in; (void)out_size;

    const size_t need = (size_t)BATCH * SEQ * HID * 2;  // 134 MB bf16 xh
    if (ws_size >= need) {
        __hip_bfloat16* xh = (__hip_bfloat16*)d_ws;
        xh_gemm_kernel<<<dim3(512), dim3(256), 0, stream>>>(x, Wxh, bxh, xh);
        rnn_recff_kernel<<<dim3(BATCH / BD), dim3(256), 0, stream>>>(
            xh, h0, Whh, Wout, bout, (float*)d_out);
    } else {
        rnn_fused_kernel<<<dim3(BATCH / BD), dim3(256), 0, stream>>>(
            x, h0, Wxh, bxh, Whh, Wout, bout, (float*)d_out);
    }
}

// Round 8
// 903.213 us; speedup vs baseline: 2.1026x; 2.1026x over previous
//
#include <hip/hip_runtime.h>
#include <hip/hip_bf16.h>

// UnrolledRNN on MI355X (gfx950) — two-phase; 8-wave split-u recurrence.
// Phase 1 (parallel, all CUs): xh[b,t,:] = x[b,t,:] @ Wxh + bxh -> bf16 in d_ws.
// Phase 2 (serial, 16 blocks x 8 waves = 512 thr): h = tanh(xh_t + h @ Whh).
//   R7 lesson: LDS spin-poll >> s_barrier cost; the ~1160cyc floor is EXPOSED
//   LATENCY at 1 wave/SIMD (MFMA blocks its wave ~20cyc, trans 1/4-rate, LDS
//   read ~120cyc). Fix: 2 waves/SIMD with HALVED per-wave work.
//   Wave (jw,u) (jw=wv&3, u=wv>>2) owns the u-half of j-slice jw:
//   acc reg r <-> j = 32jw + 8lg + 4u + r (R3-validated sigma, u fixed).
//   Per step/wave: 8B xh load, 4 ds_read_b128 (all frags), 4 MFMA (2+2 tree),
//   4 tanh, 1 ds_write_b64 (half-frag at lane*16+8u). Waves wv and wv+4 share
//   a SIMD -> each other's MFMA-block/LDS/trans latencies are hidden.
//   2-zone parity + 1 barrier/step (same safety argument as R2-R6).

#define SEQ   2048
#define HID   128
#define BATCH 256
#define BD    16

typedef __attribute__((ext_vector_type(8))) short    short8;
typedef __attribute__((ext_vector_type(4))) float    f32x4;
typedef __attribute__((ext_vector_type(4))) float    f4;
typedef __attribute__((ext_vector_type(2))) unsigned u32x2;
typedef __attribute__((ext_vector_type(4))) unsigned u32x4;

union F8 { unsigned u[4]; short8 s; };

__device__ __forceinline__ unsigned pkbf(float a, float b) {
    union { __hip_bfloat16 h[2]; unsigned u; } t;
    t.h[0] = __float2bfloat16(a);
    t.h[1] = __float2bfloat16(b);
    return t.u;
}

__device__ __forceinline__ float blo(unsigned u) {
    union { unsigned v; float f; } t; t.v = u << 16; return t.f;
}
__device__ __forceinline__ float bhi(unsigned u) {
    union { unsigned v; float f; } t; t.v = u & 0xffff0000u; return t.f;
}

__device__ __forceinline__ float tanh_fast(float x) {
    float e = __builtin_amdgcn_exp2f(x * 2.8853900817779268f);
    return 1.0f - 2.0f * __builtin_amdgcn_rcpf(e + 1.0f);
}

__device__ __forceinline__ void block_sync() {
    asm volatile("s_waitcnt lgkmcnt(0)" ::: "memory");
    __builtin_amdgcn_s_barrier();
    asm volatile("" ::: "memory");
}

#define MFMA16(A,B,C) __builtin_amdgcn_mfma_f32_16x16x32_bf16((A),(B),(C),0,0,0)

// =====================================================================
// Phase 1: xh = x @ Wxh + bxh, bf16 [BATCH*SEQ][HID] in ws (plain j order).
// =====================================================================
__launch_bounds__(256, 1)
__global__ void xh_gemm_kernel(const float* __restrict__ x,
                               const float* __restrict__ Wxh,
                               const float* __restrict__ bxh,
                               __hip_bfloat16* __restrict__ xh)
{
    const int tid  = threadIdx.x;
    const int wv   = tid >> 6;
    const int lane = tid & 63;
    const int lg   = lane >> 4;
    const int lm   = lane & 15;

    const int gw = blockIdx.x * 4 + wv;
    const int NW = gridDim.x * 4;
    const int NT = (BATCH * SEQ) / 16;

    short8 wa[8][4];
    {
        #pragma unroll
        for (int T = 0; T < 8; ++T) {
            #pragma unroll
            for (int c = 0; c < 4; ++c) {
                F8 f;
                #pragma unroll
                for (int e2 = 0; e2 < 4; ++e2) {
                    int k = 32*c + 8*lg + 2*e2;
                    f.u[e2] = pkbf(Wxh[(size_t)k*HID + 16*T + lm],
                                   Wxh[(size_t)(k+1)*HID + 16*T + lm]);
                }
                wa[T][c] = f.s;
            }
        }
    }
    float bb[8][4];
    #pragma unroll
    for (int T = 0; T < 8; ++T)
        #pragma unroll
        for (int r = 0; r < 4; ++r)
            bb[T][r] = bxh[16*T + 4*lg + r];

    for (int tile = gw; tile < NT; tile += NW) {
        const float* xp = x + (size_t)tile*16*HID + (size_t)lm*HID + 8*lg;
        f4 s[8];
        #pragma unroll
        for (int c = 0; c < 4; ++c) {
            s[2*c]   = *(const f4*)(xp + 32*c);
            s[2*c+1] = *(const f4*)(xp + 32*c + 4);
        }
        F8 xf[4];
        #pragma unroll
        for (int c = 0; c < 4; ++c) {
            xf[c].u[0] = pkbf(s[2*c][0],   s[2*c][1]);
            xf[c].u[1] = pkbf(s[2*c][2],   s[2*c][3]);
            xf[c].u[2] = pkbf(s[2*c+1][0], s[2*c+1][1]);
            xf[c].u[3] = pkbf(s[2*c+1][2], s[2*c+1][3]);
        }
        __hip_bfloat16* op = xh + (size_t)(tile*16 + lm) * HID;
        #pragma unroll
        for (int T = 0; T < 8; ++T) {
            f32x4 acc = {bb[T][0], bb[T][1], bb[T][2], bb[T][3]};
            #pragma unroll
            for (int c = 0; c < 4; ++c)
                acc = MFMA16(wa[T][c], xf[c].s, acc);
            u32x2 w;
            w[0] = pkbf(acc[0], acc[1]);
            w[1] = pkbf(acc[2], acc[3]);
            *reinterpret_cast<u32x2*>(op + 16*T + 4*lg) = w;
        }
    }
}

// =====================================================================
// Phase 2: 8-wave split-u recurrence.
// LDS: zone[P in 0..1][c in 0..3][lane][16B] at P*4096 + c*1024 + lane*16.
// Wave (jw,u) writes its half-frag (8B) at zone^1 + jw*1024 + lane*16 + 8u.
// =====================================================================

#define REC8W_STEP(S, P, POFF, TRT)                                           \
    {                                                                          \
        f32x4 a;                                                               \
        a[0] = blo(S[0]); a[1] = bhi(S[0]);                                    \
        a[2] = blo(S[1]); a[3] = bhi(S[1]);                                    \
        if ((TRT) + 4 < SEQ) S = *(const u32x2*)(xq + (POFF)*256);             \
        block_sync(); /* h_t frags complete in zone[P] */                      \
        const char* rb = lds + (P)*4096;                                       \
        short8 f0 = *(const short8*)(rb + 0*1024 + lane*16);                   \
        short8 f1 = *(const short8*)(rb + 1*1024 + lane*16);                   \
        short8 f2 = *(const short8*)(rb + 2*1024 + lane*16);                   \
        short8 f3 = *(const short8*)(rb + 3*1024 + lane*16);                   \
        f32x4 tacc = {0.f, 0.f, 0.f, 0.f};                                     \
        a    = MFMA16(whf[0], f0, a);                                          \
        tacc = MFMA16(whf[2], f2, tacc);                                       \
        a    = MFMA16(whf[1], f1, a);                                          \
        tacc = MFMA16(whf[3], f3, tacc);                                       \
        a += tacc;                                                             \
        u32x2 nf;                                                              \
        nf[0] = pkbf(tanh_fast(a[0]), tanh_fast(a[1]));                        \
        nf[1] = pkbf(tanh_fast(a[2]), tanh_fast(a[3]));                        \
        *reinterpret_cast<u32x2*>(lds + ((P)^1)*4096 + wr) = nf;               \
    }

__launch_bounds__(512, 1)
__global__ void rnn_rec8w_kernel(const __hip_bfloat16* __restrict__ xh,
                                 const float* __restrict__ h0,
                                 const float* __restrict__ Whh,
                                 const float* __restrict__ Wout,
                                 const float* __restrict__ bout,
                                 float* __restrict__ out)
{
    __shared__ __align__(16) char lds[2 * 4096];  // 2 zones x 4 frags x 64 x 16B

    const int tid  = threadIdx.x;
    const int wv   = tid >> 6;        // 0..7
    const int jw   = wv & 3;          // j-slice
    const int u    = wv >> 2;         // half within slice
    const int lane = tid & 63;
    const int lg   = lane >> 4;
    const int lm   = lane & 15;
    const int b0   = blockIdx.x * BD;

    // Whh A-frags (R3-validated sigma, u fixed per wave):
    // whf[c] lane (lg,lm) elem-pair e2 = Whh[32c+8lg+2e2 (+1)][scol],
    // scol = 32jw + 8*(lm>>2) + 4u + (lm&3).
    short8 whf[4];
    {
        const int scol = 32*jw + 8*(lm >> 2) + 4*u + (lm & 3);
        #pragma unroll
        for (int c = 0; c < 4; ++c) {
            F8 f;
            #pragma unroll
            for (int e2 = 0; e2 < 4; ++e2) {
                int k = 32*c + 8*lg + 2*e2;
                f.u[e2] = pkbf(Whh[(size_t)k*HID + scol],
                               Whh[(size_t)(k+1)*HID + scol]);
            }
            whf[c] = f.s;
        }
    }

    // LDS write offset for this wave's half-frag
    const int wr = jw*1024 + lane*16 + 8*u;

    // init zone0 from h0: this wave's 4 values = h0[b0+lm][32jw+8lg+4u+{0..3}]
    {
        const float* hp = h0 + (size_t)(b0 + lm) * HID + 32*jw + 8*lg + 4*u;
        f4 v = *(const f4*)(hp);
        u32x2 iv;
        iv[0] = pkbf(v[0], v[1]);
        iv[1] = pkbf(v[2], v[3]);
        *reinterpret_cast<u32x2*>(lds + wr) = iv;
    }

    // xh stream: 8B/lane/step at xh[b0+lm][t][32jw+8lg+4u], 4-deep prefetch
    const char* xq = (const char*)xh + (size_t)(b0 + lm) * SEQ * 256
                   + (size_t)(32*jw + 8*lg + 4*u) * 2;

    u32x2 sA = *(const u32x2*)(xq + 0*256);
    u32x2 sB = *(const u32x2*)(xq + 1*256);
    u32x2 sC = *(const u32x2*)(xq + 2*256);
    u32x2 sD = *(const u32x2*)(xq + 3*256);

    for (int t = 0; t < SEQ; t += 4) {
        REC8W_STEP(sA, 0, 4, t);
        REC8W_STEP(sB, 1, 5, t + 1);
        REC8W_STEP(sC, 0, 6, t + 2);
        REC8W_STEP(sD, 1, 7, t + 3);
        xq += 4 * 256;
    }

    // epilogue: out = h_last @ Wout + bout; h_SEQ frags in zone0.
    // Wave wv computes output tile T = wv (j_out in [16T,16T+16)).
    block_sync();
    {
        const int T = wv;
        short8 h0f = *reinterpret_cast<const short8*>(lds + 0*1024 + lane*16);
        short8 h1f = *reinterpret_cast<const short8*>(lds + 1*1024 + lane*16);
        short8 h2f = *reinterpret_cast<const short8*>(lds + 2*1024 + lane*16);
        short8 h3f = *reinterpret_cast<const short8*>(lds + 3*1024 + lane*16);

        f32x4 o = {bout[16*T + 4*lg + 0], bout[16*T + 4*lg + 1],
                   bout[16*T + 4*lg + 2], bout[16*T + 4*lg + 3]};
        #pragma unroll
        for (int c = 0; c < 4; ++c) {
            F8 f;
            #pragma unroll
            for (int e2 = 0; e2 < 4; ++e2) {
                int k = 32*c + 8*lg + 2*e2;
                f.u[e2] = pkbf(Wout[(size_t)k*HID + 16*T + lm],
                               Wout[(size_t)(k+1)*HID + 16*T + lm]);
            }
            const short8 hf = (c == 0) ? h0f : (c == 1) ? h1f : (c == 2) ? h2f : h3f;
            o = MFMA16(f.s, hf, o);
        }
        float* op = out + (size_t)(b0 + lm) * HID + 16*T + 4*lg;
        *reinterpret_cast<f4*>(op) = o;
    }
}

// =====================================================================
// Fallback: verified round-1 monolithic kernel (used if ws too small).
// =====================================================================
#define RNN_STEP(SLOT, P, POFF, TRT)                                          \
    {                                                                          \
        F8 xf[4];                                                              \
        _Pragma("unroll")                                                      \
        for (int c = 0; c < 4; ++c) {                                          \
            xf[c].u[0] = pkbf(SLOT[2*c][0],   SLOT[2*c][1]);                   \
            xf[c].u[1] = pkbf(SLOT[2*c][2],   SLOT[2*c][3]);                   \
            xf[c].u[2] = pkbf(SLOT[2*c+1][0], SLOT[2*c+1][1]);                 \
            xf[c].u[3] = pkbf(SLOT[2*c+1][2], SLOT[2*c+1][3]);                 \
        }                                                                      \
        if ((TRT) + 2 < SEQ) {                                                 \
            _Pragma("unroll")                                                  \
            for (int c = 0; c < 4; ++c) {                                      \
                SLOT[2*c]   = *(const f4*)(xq + (POFF)*HID + 32*c);            \
                SLOT[2*c+1] = *(const f4*)(xq + (POFF)*HID + 32*c + 4);        \
            }                                                                  \
        }                                                                      \
        f32x4 a0 = {bx[0][0], bx[0][1], bx[0][2], bx[0][3]};                   \
        f32x4 a1 = {bx[1][0], bx[1][1], bx[1][2], bx[1][3]};                   \
        _Pragma("unroll")                                                      \
        for (int c = 0; c < 4; ++c) {                                          \
            a0 = MFMA16(wxh[0][c], xf[c].s, a0);                               \
            a1 = MFMA16(wxh[1][c], xf[c].s, a1);                               \
        }                                                                      \
        block_sync();                                                          \
        _Pragma("unroll")                                                      \
        for (int c = 0; c < 4; ++c) {                                          \
            short8 hf = *reinterpret_cast<const short8*>(lds + (P)*4096 + rd[c]); \
            a0 = MFMA16(whh[0][c], hf, a0);                                    \
            a1 = MFMA16(whh[1][c], hf, a1);                                    \
        }                                                                      \
        u32x2 w0, w1;                                                          \
        w0[0] = pkbf(tanh_fast(a0[0]), tanh_fast(a0[1]));                      \
        w0[1] = pkbf(tanh_fast(a0[2]), tanh_fast(a0[3]));                      \
        w1[0] = pkbf(tanh_fast(a1[0]), tanh_fast(a1[1]));                      \
        w1[1] = pkbf(tanh_fast(a1[2]), tanh_fast(a1[3]));                      \
        *reinterpret_cast<u32x2*>(lds + ((P)^1)*4096 + hw[0]) = w0;            \
        *reinterpret_cast<u32x2*>(lds + ((P)^1)*4096 + hw[1]) = w1;            \
    }

__launch_bounds__(256, 1)
__global__ void rnn_fused_kernel(const float* __restrict__ x,
                                 const float* __restrict__ h0,
                                 const float* __restrict__ Wxh,
                                 const float* __restrict__ bxh,
                                 const float* __restrict__ Whh,
                                 const float* __restrict__ Wout,
                                 const float* __restrict__ bout,
                                 float* __restrict__ out)
{
    __shared__ __align__(16) char lds[2 * 4096];

    const int tid  = threadIdx.x;
    const int wv   = tid >> 6;
    const int lane = tid & 63;
    const int lg   = lane >> 4;
    const int lm   = lane & 15;
    const int b0   = blockIdx.x * BD;

    short8 wxh[2][4], whh[2][4];
    {
        const int col = 32*wv + lm;
        #pragma unroll
        for (int T = 0; T < 2; ++T) {
            #pragma unroll
            for (int c = 0; c < 4; ++c) {
                F8 fx, fh;
                #pragma unroll
                for (int e2 = 0; e2 < 4; ++e2) {
                    int k = 32*c + 8*lg + 2*e2;
                    fx.u[e2] = pkbf(Wxh[(size_t)k*HID + col + 16*T],
                                    Wxh[(size_t)(k+1)*HID + col + 16*T]);
                    fh.u[e2] = pkbf(Whh[(size_t)k*HID + col + 16*T],
                                    Whh[(size_t)(k+1)*HID + col + 16*T]);
                }
                wxh[T][c] = fx.s; whh[T][c] = fh.s;
            }
        }
    }
    float bx[2][4];
    #pragma unroll
    for (int T = 0; T < 2; ++T)
        #pragma unroll
        for (int r = 0; r < 4; ++r)
            bx[T][r] = bxh[32*wv + 16*T + 4*lg + r];

    int rd[4];
    #pragma unroll
    for (int c = 0; c < 4; ++c)
        rd[c] = (lm*256 + 64*c + 16*lg) ^ ((lm & 7) << 4);
    int hw[2];
    #pragma unroll
    for (int T = 0; T < 2; ++T)
        hw[T] = (lm*256 + 2*(32*wv + 16*T + 4*lg)) ^ ((lm & 7) << 4);

    {
        int b  = tid >> 4;
        int j0 = (tid & 15) * 8;
        const float* hp = h0 + (size_t)(b0 + b) * HID + j0;
        f4 v0 = *(const f4*)(hp);
        f4 v1 = *(const f4*)(hp + 4);
        F8 f;
        f.u[0] = pkbf(v0[0], v0[1]); f.u[1] = pkbf(v0[2], v0[3]);
        f.u[2] = pkbf(v1[0], v1[1]); f.u[3] = pkbf(v1[2], v1[3]);
        int off = (b*256 + 2*j0) ^ ((b & 7) << 4);
        *reinterpret_cast<short8*>(lds + off) = f.s;
    }

    const float* xq = x + (size_t)(b0 + lm) * SEQ * HID + 8*lg;
    f4 sA[8], sB[8];
    #pragma unroll
    for (int c = 0; c < 4; ++c) {
        sA[2*c]   = *(const f4*)(xq + 32*c);
        sA[2*c+1] = *(const f4*)(xq + 32*c + 4);
        sB[2*c]   = *(const f4*)(xq + HID + 32*c);
        sB[2*c+1] = *(const f4*)(xq + HID + 32*c + 4);
    }

    for (int t = 0; t < SEQ; t += 2) {
        RNN_STEP(sA, 0, 2, t);
        RNN_STEP(sB, 1, 3, t + 1);
        xq += 2 * HID;
    }

    block_sync();
    {
        short8 wo[2][4];
        const int col = 32*wv + lm;
        #pragma unroll
        for (int T = 0; T < 2; ++T) {
            #pragma unroll
            for (int c = 0; c < 4; ++c) {
                F8 f;
                #pragma unroll
                for (int e2 = 0; e2 < 4; ++e2) {
                    int k = 32*c + 8*lg + 2*e2;
                    f.u[e2] = pkbf(Wout[(size_t)k*HID + col + 16*T],
                                   Wout[(size_t)(k+1)*HID + col + 16*T]);
                }
                wo[T][c] = f.s;
            }
        }
        f32x4 o0 = {bout[32*wv + 4*lg + 0], bout[32*wv + 4*lg + 1],
                    bout[32*wv + 4*lg + 2], bout[32*wv + 4*lg + 3]};
        f32x4 o1 = {bout[32*wv + 16 + 4*lg + 0], bout[32*wv + 16 + 4*lg + 1],
                    bout[32*wv + 16 + 4*lg + 2], bout[32*wv + 16 + 4*lg + 3]};
        #pragma unroll
        for (int c = 0; c < 4; ++c) {
            short8 hf = *reinterpret_cast<const short8*>(lds + rd[c]);
            o0 = MFMA16(wo[0][c], hf, o0);
            o1 = MFMA16(wo[1][c], hf, o1);
        }
        float* op = out + (size_t)(b0 + lm) * HID + 32*wv + 4*lg;
        *reinterpret_cast<f4*>(op)      = o0;
        *reinterpret_cast<f4*>(op + 16) = o1;
    }
}

extern "C" void kernel_launch(void* const* d_in, const int* in_sizes, int n_in,
                              void* d_out, int out_size, void* d_ws, size_t ws_size,
                              hipStream_t stream) {
    const float* x    = (const float*)d_in[0];
    const float* h0   = (const float*)d_in[1];
    const float* Wxh  = (const float*)d_in[2];
    const float* bxh  = (const float*)d_in[3];
    const float* Whh  = (const float*)d_in[4];
    const float* Wout = (const float*)d_in[5];
    const float* bout = (const float*)d_in[6];
    (void)in_sizes; (void)n_in; (void)out_size;

    const size_t need = (size_t)BATCH * SEQ * HID * 2;  // 134 MB bf16 xh
    if (ws_size >= need) {
        __hip_bfloat16* xh = (__hip_bfloat16*)d_ws;
        xh_gemm_kernel<<<dim3(512), dim3(256), 0, stream>>>(x, Wxh, bxh, xh);
        rnn_rec8w_kernel<<<dim3(BATCH / BD), dim3(512), 0, stream>>>(
            xh, h0, Whh, Wout, bout, (float*)d_out);
    } else {
        rnn_fused_kernel<<<dim3(BATCH / BD), dim3(256), 0, stream>>>(
            x, h0, Wxh, bxh, Whh, Wout, bout, (float*)d_out);
    }
}